// Round 13
// baseline (288.637 us; speedup 1.0000x reference)
//
#include <hip/hip_runtime.h>
#include <hip/hip_bf16.h>
#include <stdint.h>
#include <stddef.h>

typedef __hip_bfloat16 bf16_t;
typedef __attribute__((ext_vector_type(8))) short short8;
typedef __attribute__((ext_vector_type(4))) short short4v;
typedef __attribute__((ext_vector_type(4))) float floatx4;
typedef __attribute__((ext_vector_type(4))) unsigned uint4v;
typedef __attribute__((ext_vector_type(2))) unsigned uint2v;

#define EMBED 1024
#define NHEAD 16
#define HDIM  64
#define BATCH 2
#define SEQ   2048
#define MTOT  (BATCH*SEQ)
#define NEG_INF (-1e30f)
// 1/sqrt(64) * log2(e): softmax carried in exp2 domain (folded into Q projection)
#define SCALE2 0.18033688011112042f

#define MFMA16(a,b,c) __builtin_amdgcn_mfma_f32_16x16x32_bf16(a,b,c,0,0,0)

static __device__ __forceinline__ short bf16_bits(float x) {
    return __builtin_bit_cast(short, __float2bfloat16(x));
}

static __device__ __forceinline__ float fast_exp2(float x) {
#if __has_builtin(__builtin_amdgcn_exp2f)
    return __builtin_amdgcn_exp2f(x);
#else
    return __expf(x * 0.6931471805599453f);
#endif
}

// two bf16 (RTNE) packed in a u32; compiler fuses to v_cvt_pk_bf16_f32 (m240)
static __device__ __forceinline__ unsigned pack_bf16x2(float lo, float hi) {
    const unsigned a = (unsigned)(unsigned short)bf16_bits(lo);
    const unsigned b = (unsigned)(unsigned short)bf16_bits(hi);
    return a | (b << 16);
}

// gfx950 permlane swaps (verified R4: absmax unchanged vs LDS path)
static __device__ __forceinline__ void permswap32(unsigned& a, unsigned& b) {
#if __has_builtin(__builtin_amdgcn_permlane32_swap)
    uint2v r = __builtin_amdgcn_permlane32_swap(a, b, false, false);
    a = r[0]; b = r[1];
#else
    asm volatile("v_permlane32_swap_b32 %0, %1" : "+v"(a), "+v"(b));
#endif
}
static __device__ __forceinline__ void permswap16(unsigned& a, unsigned& b) {
#if __has_builtin(__builtin_amdgcn_permlane16_swap)
    uint2v r = __builtin_amdgcn_permlane16_swap(a, b, false, false);
    a = r[0]; b = r[1];
#else
    asm volatile("v_permlane16_swap_b32 %0, %1" : "+v"(a), "+v"(b));
#endif
}

// async global->LDS, 16B per lane; lds ptr must be wave-uniform (HW: base + lane*16)
static __device__ __forceinline__ void async_ld16(const bf16_t* g, short* l) {
    __builtin_amdgcn_global_load_lds(
        (const __attribute__((address_space(1))) void*)g,
        (__attribute__((address_space(3))) void*)l,
        16, 0, 0);
}

static __device__ __forceinline__ void store_out(float* p, float v)  { *p = v; }
static __device__ __forceinline__ void store_out(bf16_t* p, float v) { *p = __float2bfloat16(v); }

// fp32 -> bf16 (RTNE) for q,k,v (4M each) and Wq,Wk,Wv,Wo (1M each). grid.y selects tensor.
__global__ __launch_bounds__(256)
void cvt_all(const float* __restrict__ q, const float* __restrict__ k, const float* __restrict__ v,
             const float* __restrict__ wq, const float* __restrict__ wk,
             const float* __restrict__ wv, const float* __restrict__ wo,
             bf16_t* __restrict__ Qx, bf16_t* __restrict__ Kx, bf16_t* __restrict__ Vx,
             bf16_t* __restrict__ Wqb, bf16_t* __restrict__ Wkb,
             bf16_t* __restrict__ Wvb, bf16_t* __restrict__ Wob)
{
    const float* s; bf16_t* d; int n;
    switch (blockIdx.y) {
        case 0:  s = q;  d = Qx;  n = MTOT * EMBED;  break;
        case 1:  s = k;  d = Kx;  n = MTOT * EMBED;  break;
        case 2:  s = v;  d = Vx;  n = MTOT * EMBED;  break;
        case 3:  s = wq; d = Wqb; n = EMBED * EMBED; break;
        case 4:  s = wk; d = Wkb; n = EMBED * EMBED; break;
        case 5:  s = wv; d = Wvb; n = EMBED * EMBED; break;
        default: s = wo; d = Wob; n = EMBED * EMBED; break;
    }
    const int i4 = (int)blockIdx.x * 256 + (int)threadIdx.x;   // float4 index
    if (i4 * 4 < n) {
        const float4 f = ((const float4*)s)[i4];
        short4v o;
        o[0] = bf16_bits(f.x); o[1] = bf16_bits(f.y);
        o[2] = bf16_bits(f.z); o[3] = bf16_bits(f.w);
        ((short4v*)d)[i4] = o;
    }
}

// C[M,N] = (A[M,K] @ W[N,K]^T + bias) * scale, bf16 in, fp32 accumulate.
// M=4096, N=K=1024 fixed. BM x 128 tile, BK=64 (two 32-col halves per barrier pair).
// 256 thr (4 waves 2x2). VT=true: transposed output (for V: [b, d_global, s]).
// v9 (R12-verified): shared staging hoisted to callers (one 32KB set, not one per
// template instantiation); XCD-chunked block swizzle for A-panel L2 locality.
template <typename OutT, bool VT, int BM>
static __device__ __forceinline__ void gemm_tile(
    const bf16_t* __restrict__ A, const bf16_t* __restrict__ W,
    const float* __restrict__ bias, OutT* __restrict__ C, const float scale,
    short* __restrict__ As, short* __restrict__ Bs)
{
    constexpr int MI  = BM >> 5;            // A-frags per wave (4 or 2)
    constexpr int RPW = BM >> 2;            // A rows staged per wave
    constexpr int NBM = 4096 / BM;          // 32 or 64
    constexpr int BMC = NBM / 8;            // bm chunk per XCD (4 or 8)
    const int N = 1024, K = 1024;

    const int tid  = threadIdx.x;
    const int wave = tid >> 6;
    const int lane = tid & 63;
    // XCD-chunked swizzle (bijective: bid = xcd + 8*(bml + BMC*bn))
    const int bid = (int)blockIdx.x;
    const int xcd = bid & 7;
    const int k8  = bid >> 3;
    const int bm  = xcd * BMC + (k8 & (BMC - 1));
    const int bn  = k8 / BMC;
    const int m0 = bm * BM, n0 = bn << 7;

    const int wm = ((wave >> 1) & 1) * (BM >> 1);
    const int wn = (wave & 1) << 6;

    floatx4 acc[MI][4] = {};

    const int srowA = wave * RPW + (lane >> 2);
    const int srowB = (wave << 5) + (lane >> 2);
    const int scol  = (lane & 3) << 3;            // element col: 0,8,16,24
    const bf16_t* gA = A + (size_t)(m0 + srowA) * K + scol;
    const bf16_t* gB = W + (size_t)(n0 + srowB) * K + scol;

    const int fr = lane & 15;
    const int fk = (lane >> 4) << 3;

    for (int k0 = 0; k0 < K; k0 += 64) {
        __syncthreads();
        short* a0 = As + wave * RPW * 32;             // half 0
        short* a1 = As + BM * 32 + wave * RPW * 32;   // half 1
        short* b0 = Bs + (wave << 10);
        short* b1 = Bs + 128 * 32 + (wave << 10);
        async_ld16(gA,      a0);
        async_ld16(gA + 32, a1);
        if constexpr (BM == 128) {
            async_ld16(gA + (size_t)16 * K,      a0 + 512);
            async_ld16(gA + (size_t)16 * K + 32, a1 + 512);
        }
        async_ld16(gB,      b0);
        async_ld16(gB + 32, b1);
        async_ld16(gB + (size_t)16 * K,      b0 + 512);
        async_ld16(gB + (size_t)16 * K + 32, b1 + 512);
        gA += 64; gB += 64;
        __syncthreads();                      // drains vmcnt before barrier (m97-verified)

        #pragma unroll
        for (int hh = 0; hh < 2; ++hh) {
            short8 af[MI], bfr[4];
            #pragma unroll
            for (int i = 0; i < MI; ++i)
                af[i] = *(const short8*)&As[hh * BM * 32 + (wm + (i << 4) + fr) * 32 + fk];
            #pragma unroll
            for (int j = 0; j < 4; ++j)
                bfr[j] = *(const short8*)&Bs[hh * 128 * 32 + (wn + (j << 4) + fr) * 32 + fk];
            #pragma unroll
            for (int i = 0; i < MI; ++i)
                #pragma unroll
                for (int j = 0; j < 4; ++j)
                    acc[i][j] = MFMA16(af[i], bfr[j], acc[i][j]);
        }
    }

    // epilogue: C/D layout col=lane&15, row=quad*4+r
    const int q4 = (lane >> 4) << 2;
    #pragma unroll
    for (int j = 0; j < 4; ++j) {
        const int n = n0 + wn + (j << 4) + fr;
        const float bv = bias[n];
        #pragma unroll
        for (int i = 0; i < MI; ++i) {
            const int mb = m0 + wm + (i << 4) + q4;
            if (VT) {
                const int bb = mb >> 11, ss = mb & 2047;
                short4v pk;
                #pragma unroll
                for (int r = 0; r < 4; ++r)
                    pk[r] = bf16_bits((acc[i][j][r] + bv) * scale);
                *(short4v*)((bf16_t*)C + ((size_t)(bb * 1024 + n) << 11) + ss) = pk;
            } else {
                #pragma unroll
                for (int r = 0; r < 4; ++r)
                    store_out(&C[(size_t)(mb + r) * N + n], (acc[i][j][r] + bv) * scale);
            }
        }
    }
}

__global__ __launch_bounds__(256)
void qkv_proj(const bf16_t* __restrict__ xq, const bf16_t* __restrict__ xk,
              const bf16_t* __restrict__ xv,
              const bf16_t* __restrict__ Wq, const bf16_t* __restrict__ Wk,
              const bf16_t* __restrict__ Wv,
              const float* __restrict__ bq, const float* __restrict__ bk,
              const float* __restrict__ bv,
              bf16_t* __restrict__ Qp, bf16_t* __restrict__ Kp, bf16_t* __restrict__ Vtp)
{
    // ONE shared staging set for all branches (R12-verified: was duplicated per
    // template instantiation -> 64KB/block, halved occupancy)
    __shared__ alignas(16) short As[128 * 64];
    __shared__ alignas(16) short Bs[128 * 64];
    // Q carries the softmax scale (exp2-domain): folded here, free in attn hot loop
    if (blockIdx.z == 0)      gemm_tile<bf16_t, false, 128>(xq, Wq, bq, Qp, SCALE2, As, Bs);
    else if (blockIdx.z == 1) gemm_tile<bf16_t, false, 128>(xk, Wk, bk, Kp, 1.0f, As, Bs);
    else                      gemm_tile<bf16_t, true , 128>(xv, Wv, bv, Vtp, 1.0f, As, Bs);
}

__global__ __launch_bounds__(256)
void out_proj(const bf16_t* __restrict__ AO, const bf16_t* __restrict__ Wo,
              const float* __restrict__ bo, float* __restrict__ out)
{
    __shared__ alignas(16) short As[64 * 64];
    __shared__ alignas(16) short Bs[128 * 64];
    gemm_tile<float, false, 64>(AO, Wo, bo, out, 1.0f, As, Bs);
}

// Flash attention, causal. QK^T as S^T = K·Q^T (C-layout: q = lane&15).
// v10: v8 with the per-iteration serial chain attacked two ways (R12 analysis:
//   VALUBusy 37% fully accounted by softmax work; 60% of time = exposed chain
//   latency at ~1.35 waves/SIMD):
//   (1) K+V register double-buffer restored -- next chunk's 8 scatter loads
//       issued at iteration TOP (ping-pong reg sets). Spill headroom verified:
//       R12 working set 160/256 at launch_bounds(256,2); +64 VGPR fits.
//   (2) ALL s_setprio removed from the loop -- the 6 side-effecting toggles per
//       u-iteration fenced compiler code motion, preventing u+1's independent QK
//       MFMAs from hiding under u's serial softmax (m190: setprio null/negative
//       without phase-diverse waves anyway).
//   Structure (R9-R12 verified): 1024 blocks x 4 waves; waves split the q-tile's
//   kv range in quarters; partials combined IN LDS (waves 1-3 publish O/m/l,
//   wave 0 combines in regs). Zero extra HBM traffic, no combine kernel.
//  - permlane in-register P^T (R4-verified), O^T layout, defer-max gate,
//    per-lane l partials.
//  - masked chunks (kv >= q0): c >= nch-2 in a short second loop (offb 0 / -32).
//  - tail prefetch past c1 reads in-workspace garbage (never consumed; memory valid).
__global__ __launch_bounds__(256, 2)
void attn_causal(const bf16_t* __restrict__ Qp, const bf16_t* __restrict__ Kp,
                 const bf16_t* __restrict__ Vt, bf16_t* __restrict__ AO)
{
    __shared__ alignas(16) float Obuf[3][64][68];  // partials of waves 1..3; 272B rows
    __shared__ float Mbuf[4][64];
    __shared__ float Lbuf[4][64];

    const int tid  = (int)threadIdx.x;
    const int wave = tid >> 6;            // 0..3: kv quarter
    const int lane = tid & 63;
    const int bid  = (int)blockIdx.x;
    const int bh   = bid & 31;            // bh%8 == XCD for all blocks of this head
    const int tile = 31 - (bid >> 5);     // longest-first
    const int b = bh >> 4, h = bh & 15;
    const int q0  = tile << 6;
    const int nch = 2 * tile + 2;
    const int c0  = (wave * nch) >> 2;
    const int c1  = ((wave + 1) * nch) >> 2;
    const int d0  = nch - 2;              // first diag-masked chunk

    const int fr   = lane & 15;
    const int quad = lane >> 4;
    const int fk   = quad << 3;

    // Q B-frags for 4 subtiles (rows q0 + u*16 + fr), Q pre-scaled by SCALE2
    const bf16_t* Qb = Qp + (size_t)(b * SEQ + q0 + fr) * EMBED + h * HDIM;
    short8 aq[4][2];
    #pragma unroll
    for (int u = 0; u < 4; ++u) {
        aq[u][0] = *(const short8*)(Qb + (size_t)(u * 16) * EMBED + fk);
        aq[u][1] = *(const short8*)(Qb + (size_t)(u * 16) * EMBED + 32 + fk);
    }

    const bf16_t* Kbase = Kp + (size_t)(b * SEQ) * EMBED + h * HDIM;
    const bf16_t* Vbase = Vt + ((size_t)(b * 1024 + h * HDIM) << 11);

    floatx4 o[4][4] = {};                     // O^T[u][d=t*16+quad*4+r][q=fr]
    float m[4] = {NEG_INF, NEG_INF, NEG_INF, NEG_INF};
    float l[4] = {};

    // Softmax for one subtile -> PV B-frag (P^T[kv][q]) via permlane quad-transpose.
    auto smax_pb = [&](const floatx4& sA, const floatx4& sB, float& m_u, float& l_u,
                       floatx4* o_u, const bool masked, const int off) -> short8 {
        float v0[4], v1[4];
        #pragma unroll
        for (int rr = 0; rr < 4; ++rr) {
            float a  = sA[rr];
            float bb = sB[rr];
            if (masked) {
                const int kq = (quad << 2) + rr;
                if (kq > off + fr)      a  = NEG_INF;
                if (kq + 16 > off + fr) bb = NEG_INF;
            }
            v0[rr] = a; v1[rr] = bb;
        }
        float mx = fmaxf(fmaxf(fmaxf(v0[0], v0[1]), fmaxf(v0[2], v0[3])),
                         fmaxf(fmaxf(v1[0], v1[1]), fmaxf(v1[2], v1[3])));
        if (__any(mx > m_u + 8.0f)) {             // rare path (~once per wave)
            mx = fmaxf(mx, __shfl_xor(mx, 16, 64));
            mx = fmaxf(mx, __shfl_xor(mx, 32, 64));
            const float mn = fmaxf(m_u, mx);
            const float al = fast_exp2(m_u - mn);
            m_u = mn;
            l_u *= al;
            #pragma unroll
            for (int t = 0; t < 4; ++t)           // O^T: q = fr for ALL values
                #pragma unroll
                for (int rr = 0; rr < 4; ++rr) o_u[t][rr] *= al;
        }
        float ls = 0.f;
        #pragma unroll
        for (int rr = 0; rr < 4; ++rr) {
            v0[rr] = fast_exp2(v0[rr] - m_u);     // bounded by 2^8 (defer-max)
            v1[rr] = fast_exp2(v1[rr] - m_u);
            ls += v0[rr] + v1[rr];
        }
        l_u += ls;                                // per-lane partial, no shfl
        unsigned c0p = pack_bf16x2(v0[0], v0[1]);
        unsigned c1p = pack_bf16x2(v0[2], v0[3]);
        unsigned d0p = pack_bf16x2(v1[0], v1[1]);
        unsigned d1p = pack_bf16x2(v1[2], v1[3]);
        permswap32(c0p, d0p);
        permswap32(c1p, d1p);
        permswap16(c0p, d0p);
        permswap16(c1p, d1p);
        uint4v wv; wv[0] = c0p; wv[1] = c1p; wv[2] = d0p; wv[3] = d1p;
        return __builtin_bit_cast(short8, wv);
    };

// Load one chunk's K (4 frags) + V (4 frags) into named regs
#define KVLOAD(K0_, K1_, K2_, K3_, V0_, V1_, V2_, V3_, CC) do {              \
        const int kvq_ = (CC) << 5;                                          \
        const bf16_t* Kr0_ = Kbase + (size_t)(kvq_ + fr) * EMBED;            \
        const bf16_t* Kr1_ = Kr0_ + (size_t)16 * EMBED;                      \
        K0_ = *(const short8*)(Kr0_ + fk);                                   \
        K1_ = *(const short8*)(Kr0_ + 32 + fk);                              \
        K2_ = *(const short8*)(Kr1_ + fk);                                   \
        K3_ = *(const short8*)(Kr1_ + 32 + fk);                              \
        V0_ = *(const short8*)(Vbase + ((size_t)(fr)      << 11) + kvq_ + fk); \
        V1_ = *(const short8*)(Vbase + ((size_t)(16 + fr) << 11) + kvq_ + fk); \
        V2_ = *(const short8*)(Vbase + ((size_t)(32 + fr) << 11) + kvq_ + fk); \
        V3_ = *(const short8*)(Vbase + ((size_t)(48 + fr) << 11) + kvq_ + fk); \
    } while (0)

// One kv chunk using current regs; prefetch chunk CC+1 into next regs FIRST
// (loads in flight across the whole iteration's compute). No setprio (v10).
#define ITER(K0_, K1_, K2_, K3_, V0_, V1_, V2_, V3_,                         \
             N0_, N1_, N2_, N3_, N4_, N5_, N6_, N7_, CC, MASKED, OFFB) do {  \
        if ((CC) + 1 < c1)                                                   \
            KVLOAD(N0_, N1_, N2_, N3_, N4_, N5_, N6_, N7_, (CC) + 1);        \
        _Pragma("unroll")                                                    \
        for (int u = 0; u < 4; ++u) {                                        \
            floatx4 z0 = {}, z1 = {};                                        \
            z0 = MFMA16(K0_, aq[u][0], z0); z0 = MFMA16(K1_, aq[u][1], z0);  \
            z1 = MFMA16(K2_, aq[u][0], z1); z1 = MFMA16(K3_, aq[u][1], z1);  \
            const short8 pb = smax_pb(z0, z1, m[u], l[u], o[u],              \
                                      MASKED, u * 16 + (OFFB));              \
            o[u][0] = MFMA16(V0_, pb, o[u][0]);                              \
            o[u][1] = MFMA16(V1_, pb, o[u][1]);                              \
            o[u][2] = MFMA16(V2_, pb, o[u][2]);                              \
            o[u][3] = MFMA16(V3_, pb, o[u][3]);                              \
        }                                                                    \
    } while (0)

    if (c1 > c0) {
        short8 ka0, ka1, ka2, ka3, va0, va1, va2, va3;
        short8 kb0, kb1, kb2, kb3, vb0, vb1, vb2, vb3;
        KVLOAD(ka0, ka1, ka2, ka3, va0, va1, va2, va3, c0);

        int c = c0;
        bool ina = true;
        const int dcl = (d0 < c1) ? d0 : c1;     // clamp masked start into range
        const int cmu = (dcl > c0) ? dcl : c0;   // unmasked end
        for (; c < cmu; ++c) {
            if (ina) ITER(ka0, ka1, ka2, ka3, va0, va1, va2, va3,
                          kb0, kb1, kb2, kb3, vb0, vb1, vb2, vb3, c, false, 0);
            else     ITER(kb0, kb1, kb2, kb3, vb0, vb1, vb2, vb3,
                          ka0, ka1, ka2, ka3, va0, va1, va2, va3, c, false, 0);
            ina = !ina;
        }
        for (; c < c1; ++c) {
            const int offb = (c == d0) ? 0 : -32;
            if (ina) ITER(ka0, ka1, ka2, ka3, va0, va1, va2, va3,
                          kb0, kb1, kb2, kb3, vb0, vb1, vb2, vb3, c, true, offb);
            else     ITER(kb0, kb1, kb2, kb3, vb0, vb1, vb2, vb3,
                          ka0, ka1, ka2, ka3, va0, va1, va2, va3, c, true, offb);
            ina = !ina;
        }
    }

#undef ITER
#undef KVLOAD

    // deferred cross-quad l reduction (once)
    #pragma unroll
    for (int u = 0; u < 4; ++u) {
        float t = __shfl_xor(l[u], 16, 64); l[u] += t;
        t = __shfl_xor(l[u], 32, 64);       l[u] += t;
    }

    // publish partials: waves 1..3 -> LDS O; all waves -> m,l
    if (wave != 0) {
        #pragma unroll
        for (int u = 0; u < 4; ++u)
            #pragma unroll
            for (int t = 0; t < 4; ++t)
                *(floatx4*)&Obuf[wave - 1][u * 16 + fr][(t << 4) + (quad << 2)] = o[u][t];
    }
    if (quad == 0) {
        #pragma unroll
        for (int u = 0; u < 4; ++u) {
            Mbuf[wave][u * 16 + fr] = m[u];
            Lbuf[wave][u * 16 + fr] = l[u];
        }
    }
    __syncthreads();

    if (wave == 0) {
        // 4-way combine: O = sum_s w_s O_s / sum_s w_s l_s, w_s = 2^(m_s - M)
        #pragma unroll
        for (int u = 0; u < 4; ++u) {
            const int row = u * 16 + fr;
            const float m1 = Mbuf[1][row], m2 = Mbuf[2][row], m3 = Mbuf[3][row];
            const float l1 = Lbuf[1][row], l2 = Lbuf[2][row], l3 = Lbuf[3][row];
            const float M  = fmaxf(fmaxf(m[u], m1), fmaxf(m2, m3));
            const float w0 = fast_exp2(m[u] - M);
            const float w1 = fast_exp2(m1 - M);
            const float w2 = fast_exp2(m2 - M);
            const float w3 = fast_exp2(m3 - M);
            const float rd = 1.0f / (w0 * l[u] + w1 * l1 + w2 * l2 + w3 * l3);
            // no quad term in the base -- col below carries it (R8 bugfix)
            bf16_t* outp = AO + (size_t)(b * SEQ + q0 + row) * EMBED + h * HDIM;
            #pragma unroll
            for (int t = 0; t < 4; ++t) {
                const int col = (t << 4) + (quad << 2);
                floatx4 acc = o[u][t];
                const floatx4 p1 = *(const floatx4*)&Obuf[0][row][col];
                const floatx4 p2 = *(const floatx4*)&Obuf[1][row][col];
                const floatx4 p3 = *(const floatx4*)&Obuf[2][row][col];
                short4v pk;
                #pragma unroll
                for (int rr = 0; rr < 4; ++rr) {
                    const float v = w0 * acc[rr] + w1 * p1[rr] + w2 * p2[rr] + w3 * p3[rr];
                    pk[rr] = bf16_bits(v * rd);
                }
                *(short4v*)(outp + col) = pk;
            }
        }
    }
}

extern "C" void kernel_launch(void* const* d_in, const int* in_sizes, int n_in,
                              void* d_out, int out_size, void* d_ws, size_t ws_size,
                              hipStream_t stream)
{
    (void)in_sizes; (void)n_in; (void)out_size; (void)ws_size;
    const float* q  = (const float*)d_in[0];
    const float* k  = (const float*)d_in[1];
    const float* v  = (const float*)d_in[2];
    const float* Wq = (const float*)d_in[3];
    const float* bq = (const float*)d_in[4];
    const float* Wk = (const float*)d_in[5];
    const float* bk = (const float*)d_in[6];
    const float* Wv = (const float*)d_in[7];
    const float* bv = (const float*)d_in[8];
    const float* Wo = (const float*)d_in[9];
    const float* bo = (const float*)d_in[10];
    // d_in[11] = attn_mask: fixed causal tril, handled analytically.

    const size_t NX = (size_t)MTOT * EMBED;   // 4M
    const size_t NW = (size_t)EMBED * EMBED;  // 1M
    bf16_t* Qx  = (bf16_t*)d_ws;
    bf16_t* Kx  = Qx  + NX;
    bf16_t* Vx  = Kx  + NX;
    bf16_t* Wqb = Vx  + NX;
    bf16_t* Wkb = Wqb + NW;
    bf16_t* Wvb = Wkb + NW;
    bf16_t* Wob = Wvb + NW;
    bf16_t* Qp  = Wob + NW;
    bf16_t* Kp  = Qp  + NX;
    bf16_t* Vtp = Kp  + NX;   // transposed: [b*1024 + d_global][s]
    bf16_t* AO  = Vtp + NX;   // total 32M bf16 = 64 MB

    dim3 blk(256);
    cvt_all<<<dim3(4096, 7), blk, 0, stream>>>(q, k, v, Wq, Wk, Wv, Wo,
                                               Qx, Kx, Vx, Wqb, Wkb, Wvb, Wob);
    qkv_proj<<<dim3(256, 1, 3), blk, 0, stream>>>(Qx, Kx, Vx, Wqb, Wkb, Wvb,
                                                  bq, bk, bv, Qp, Kp, Vtp);
    attn_causal<<<dim3(1024), blk, 0, stream>>>(Qp, Kp, Vtp, AO);
    out_proj<<<dim3(512), blk, 0, stream>>>(AO, Wob, bo, (float*)d_out);
}

// Round 14
// 232.562 us; speedup vs baseline: 1.2411x; 1.2411x over previous
//
#include <hip/hip_runtime.h>
#include <hip/hip_bf16.h>
#include <stdint.h>
#include <stddef.h>

typedef __hip_bfloat16 bf16_t;
typedef __attribute__((ext_vector_type(8))) short short8;
typedef __attribute__((ext_vector_type(4))) short short4v;
typedef __attribute__((ext_vector_type(4))) float floatx4;
typedef __attribute__((ext_vector_type(4))) unsigned uint4v;
typedef __attribute__((ext_vector_type(2))) unsigned uint2v;

#define EMBED 1024
#define NHEAD 16
#define HDIM  64
#define BATCH 2
#define SEQ   2048
#define MTOT  (BATCH*SEQ)
#define NEG_INF (-1e30f)
// 1/sqrt(64) * log2(e): softmax carried in exp2 domain (folded into Q projection)
#define SCALE2 0.18033688011112042f

#define MFMA16(a,b,c) __builtin_amdgcn_mfma_f32_16x16x32_bf16(a,b,c,0,0,0)

static __device__ __forceinline__ short bf16_bits(float x) {
    return __builtin_bit_cast(short, __float2bfloat16(x));
}

static __device__ __forceinline__ float fast_exp2(float x) {
#if __has_builtin(__builtin_amdgcn_exp2f)
    return __builtin_amdgcn_exp2f(x);
#else
    return __expf(x * 0.6931471805599453f);
#endif
}

// two bf16 (RTNE) packed in a u32; compiler fuses to v_cvt_pk_bf16_f32 (m240)
static __device__ __forceinline__ unsigned pack_bf16x2(float lo, float hi) {
    const unsigned a = (unsigned)(unsigned short)bf16_bits(lo);
    const unsigned b = (unsigned)(unsigned short)bf16_bits(hi);
    return a | (b << 16);
}

// gfx950 permlane swaps (verified R4: absmax unchanged vs LDS path)
static __device__ __forceinline__ void permswap32(unsigned& a, unsigned& b) {
#if __has_builtin(__builtin_amdgcn_permlane32_swap)
    uint2v r = __builtin_amdgcn_permlane32_swap(a, b, false, false);
    a = r[0]; b = r[1];
#else
    asm volatile("v_permlane32_swap_b32 %0, %1" : "+v"(a), "+v"(b));
#endif
}
static __device__ __forceinline__ void permswap16(unsigned& a, unsigned& b) {
#if __has_builtin(__builtin_amdgcn_permlane16_swap)
    uint2v r = __builtin_amdgcn_permlane16_swap(a, b, false, false);
    a = r[0]; b = r[1];
#else
    asm volatile("v_permlane16_swap_b32 %0, %1" : "+v"(a), "+v"(b));
#endif
}

// async global->LDS, 16B per lane; lds ptr must be wave-uniform (HW: base + lane*16)
static __device__ __forceinline__ void async_ld16(const bf16_t* g, short* l) {
    __builtin_amdgcn_global_load_lds(
        (const __attribute__((address_space(1))) void*)g,
        (__attribute__((address_space(3))) void*)l,
        16, 0, 0);
}

static __device__ __forceinline__ void store_out(float* p, float v)  { *p = v; }
static __device__ __forceinline__ void store_out(bf16_t* p, float v) { *p = __float2bfloat16(v); }

// fp32 -> bf16 (RTNE) for q,k,v (4M each) and Wq,Wk,Wv,Wo (1M each). grid.y selects tensor.
__global__ __launch_bounds__(256)
void cvt_all(const float* __restrict__ q, const float* __restrict__ k, const float* __restrict__ v,
             const float* __restrict__ wq, const float* __restrict__ wk,
             const float* __restrict__ wv, const float* __restrict__ wo,
             bf16_t* __restrict__ Qx, bf16_t* __restrict__ Kx, bf16_t* __restrict__ Vx,
             bf16_t* __restrict__ Wqb, bf16_t* __restrict__ Wkb,
             bf16_t* __restrict__ Wvb, bf16_t* __restrict__ Wob)
{
    const float* s; bf16_t* d; int n;
    switch (blockIdx.y) {
        case 0:  s = q;  d = Qx;  n = MTOT * EMBED;  break;
        case 1:  s = k;  d = Kx;  n = MTOT * EMBED;  break;
        case 2:  s = v;  d = Vx;  n = MTOT * EMBED;  break;
        case 3:  s = wq; d = Wqb; n = EMBED * EMBED; break;
        case 4:  s = wk; d = Wkb; n = EMBED * EMBED; break;
        case 5:  s = wv; d = Wvb; n = EMBED * EMBED; break;
        default: s = wo; d = Wob; n = EMBED * EMBED; break;
    }
    const int i4 = (int)blockIdx.x * 256 + (int)threadIdx.x;   // float4 index
    if (i4 * 4 < n) {
        const float4 f = ((const float4*)s)[i4];
        short4v o;
        o[0] = bf16_bits(f.x); o[1] = bf16_bits(f.y);
        o[2] = bf16_bits(f.z); o[3] = bf16_bits(f.w);
        ((short4v*)d)[i4] = o;
    }
}

// C[M,N] = (A[M,K] @ W[N,K]^T + bias) * scale, bf16 in, fp32 accumulate.
// M=4096, N=K=1024 fixed. BM x 128 tile, BK=64 (two 32-col halves per barrier pair).
// 256 thr (4 waves 2x2). VT=true: transposed output (for V: [b, d_global, s]).
// v9 (R12-verified): shared staging hoisted to callers (one 32KB set, not one per
// template instantiation); XCD-chunked block swizzle for A-panel L2 locality.
template <typename OutT, bool VT, int BM>
static __device__ __forceinline__ void gemm_tile(
    const bf16_t* __restrict__ A, const bf16_t* __restrict__ W,
    const float* __restrict__ bias, OutT* __restrict__ C, const float scale,
    short* __restrict__ As, short* __restrict__ Bs)
{
    constexpr int MI  = BM >> 5;            // A-frags per wave (4 or 2)
    constexpr int RPW = BM >> 2;            // A rows staged per wave
    constexpr int NBM = 4096 / BM;          // 32 or 64
    constexpr int BMC = NBM / 8;            // bm chunk per XCD (4 or 8)
    const int N = 1024, K = 1024;

    const int tid  = threadIdx.x;
    const int wave = tid >> 6;
    const int lane = tid & 63;
    // XCD-chunked swizzle (bijective: bid = xcd + 8*(bml + BMC*bn))
    const int bid = (int)blockIdx.x;
    const int xcd = bid & 7;
    const int k8  = bid >> 3;
    const int bm  = xcd * BMC + (k8 & (BMC - 1));
    const int bn  = k8 / BMC;
    const int m0 = bm * BM, n0 = bn << 7;

    const int wm = ((wave >> 1) & 1) * (BM >> 1);
    const int wn = (wave & 1) << 6;

    floatx4 acc[MI][4] = {};

    const int srowA = wave * RPW + (lane >> 2);
    const int srowB = (wave << 5) + (lane >> 2);
    const int scol  = (lane & 3) << 3;            // element col: 0,8,16,24
    const bf16_t* gA = A + (size_t)(m0 + srowA) * K + scol;
    const bf16_t* gB = W + (size_t)(n0 + srowB) * K + scol;

    const int fr = lane & 15;
    const int fk = (lane >> 4) << 3;

    for (int k0 = 0; k0 < K; k0 += 64) {
        __syncthreads();
        short* a0 = As + wave * RPW * 32;             // half 0
        short* a1 = As + BM * 32 + wave * RPW * 32;   // half 1
        short* b0 = Bs + (wave << 10);
        short* b1 = Bs + 128 * 32 + (wave << 10);
        async_ld16(gA,      a0);
        async_ld16(gA + 32, a1);
        if constexpr (BM == 128) {
            async_ld16(gA + (size_t)16 * K,      a0 + 512);
            async_ld16(gA + (size_t)16 * K + 32, a1 + 512);
        }
        async_ld16(gB,      b0);
        async_ld16(gB + 32, b1);
        async_ld16(gB + (size_t)16 * K,      b0 + 512);
        async_ld16(gB + (size_t)16 * K + 32, b1 + 512);
        gA += 64; gB += 64;
        __syncthreads();                      // drains vmcnt before barrier (m97-verified)

        #pragma unroll
        for (int hh = 0; hh < 2; ++hh) {
            short8 af[MI], bfr[4];
            #pragma unroll
            for (int i = 0; i < MI; ++i)
                af[i] = *(const short8*)&As[hh * BM * 32 + (wm + (i << 4) + fr) * 32 + fk];
            #pragma unroll
            for (int j = 0; j < 4; ++j)
                bfr[j] = *(const short8*)&Bs[hh * 128 * 32 + (wn + (j << 4) + fr) * 32 + fk];
            #pragma unroll
            for (int i = 0; i < MI; ++i)
                #pragma unroll
                for (int j = 0; j < 4; ++j)
                    acc[i][j] = MFMA16(af[i], bfr[j], acc[i][j]);
        }
    }

    // epilogue: C/D layout col=lane&15, row=quad*4+r
    const int q4 = (lane >> 4) << 2;
    #pragma unroll
    for (int j = 0; j < 4; ++j) {
        const int n = n0 + wn + (j << 4) + fr;
        const float bv = bias[n];
        #pragma unroll
        for (int i = 0; i < MI; ++i) {
            const int mb = m0 + wm + (i << 4) + q4;
            if (VT) {
                const int bb = mb >> 11, ss = mb & 2047;
                short4v pk;
                #pragma unroll
                for (int r = 0; r < 4; ++r)
                    pk[r] = bf16_bits((acc[i][j][r] + bv) * scale);
                *(short4v*)((bf16_t*)C + ((size_t)(bb * 1024 + n) << 11) + ss) = pk;
            } else {
                #pragma unroll
                for (int r = 0; r < 4; ++r)
                    store_out(&C[(size_t)(mb + r) * N + n], (acc[i][j][r] + bv) * scale);
            }
        }
    }
}

__global__ __launch_bounds__(256)
void qkv_proj(const bf16_t* __restrict__ xq, const bf16_t* __restrict__ xk,
              const bf16_t* __restrict__ xv,
              const bf16_t* __restrict__ Wq, const bf16_t* __restrict__ Wk,
              const bf16_t* __restrict__ Wv,
              const float* __restrict__ bq, const float* __restrict__ bk,
              const float* __restrict__ bv,
              bf16_t* __restrict__ Qp, bf16_t* __restrict__ Kp, bf16_t* __restrict__ Vtp)
{
    // ONE shared staging set for all branches (R12-verified: was duplicated per
    // template instantiation -> 64KB/block, halved occupancy)
    __shared__ alignas(16) short As[128 * 64];
    __shared__ alignas(16) short Bs[128 * 64];
    // Q carries the softmax scale (exp2-domain): folded here, free in attn hot loop
    if (blockIdx.z == 0)      gemm_tile<bf16_t, false, 128>(xq, Wq, bq, Qp, SCALE2, As, Bs);
    else if (blockIdx.z == 1) gemm_tile<bf16_t, false, 128>(xk, Wk, bk, Kp, 1.0f, As, Bs);
    else                      gemm_tile<bf16_t, true , 128>(xv, Wv, bv, Vtp, 1.0f, As, Bs);
}

__global__ __launch_bounds__(256)
void out_proj(const bf16_t* __restrict__ AO, const bf16_t* __restrict__ Wo,
              const float* __restrict__ bo, float* __restrict__ out)
{
    __shared__ alignas(16) short As[64 * 64];
    __shared__ alignas(16) short Bs[128 * 64];
    gemm_tile<float, false, 64>(AO, Wo, bo, out, 1.0f, As, Bs);
}

// Flash attention, causal. QK^T as S^T = K·Q^T (C-layout: q = lane&15).
// v11: R12's v8 (the 51.4us / 233us-total verified build) + register-NEUTRAL
//   K rotation: kf0-3 are persistent; chunk c+1's K is reloaded IN PLACE right
//   after its last use (u=3's QK MFMAs), so the load flies under u=3's
//   softmax+PV and next iter's V loads (~600cy cover) instead of stalling the
//   first QK of iter c+1. No ping-pong set -> no spill (R13 lesson: the
//   allocator caps arch VGPRs ~128 and spills past it; worst case here is
//   +16 transient = 112+64 accum, under the cap).
//   V loads stay at iteration top: first use is after u=0's softmax (~400cy
//   cover already). setprio kept (in the verified 51.4us build; waves are
//   phase-diverse where m191 showed +4-7%).
//   Structure (R9-R12 verified): 1024 blocks x 4 waves; waves split the q-tile's
//   kv range in quarters; partials combined IN LDS (waves 1-3 publish O/m/l,
//   wave 0 combines in regs). Zero extra HBM traffic, no combine kernel.
//  - permlane in-register P^T (R4-verified), O^T layout, defer-max gate,
//    per-lane l partials.
//  - masked chunks (kv >= q0): c >= nch-2 in a short second loop (offb 0 / -32).
__global__ __launch_bounds__(256, 2)
void attn_causal(const bf16_t* __restrict__ Qp, const bf16_t* __restrict__ Kp,
                 const bf16_t* __restrict__ Vt, bf16_t* __restrict__ AO)
{
    __shared__ alignas(16) float Obuf[3][64][68];  // partials of waves 1..3; 272B rows
    __shared__ float Mbuf[4][64];
    __shared__ float Lbuf[4][64];

    const int tid  = (int)threadIdx.x;
    const int wave = tid >> 6;            // 0..3: kv quarter
    const int lane = tid & 63;
    const int bid  = (int)blockIdx.x;
    const int bh   = bid & 31;            // bh%8 == XCD for all blocks of this head
    const int tile = 31 - (bid >> 5);     // longest-first
    const int b = bh >> 4, h = bh & 15;
    const int q0  = tile << 6;
    const int nch = 2 * tile + 2;
    const int c0  = (wave * nch) >> 2;
    const int c1  = ((wave + 1) * nch) >> 2;
    const int d0  = nch - 2;              // first diag-masked chunk

    const int fr   = lane & 15;
    const int quad = lane >> 4;
    const int fk   = quad << 3;

    // Q B-frags for 4 subtiles (rows q0 + u*16 + fr), Q pre-scaled by SCALE2
    const bf16_t* Qb = Qp + (size_t)(b * SEQ + q0 + fr) * EMBED + h * HDIM;
    short8 aq[4][2];
    #pragma unroll
    for (int u = 0; u < 4; ++u) {
        aq[u][0] = *(const short8*)(Qb + (size_t)(u * 16) * EMBED + fk);
        aq[u][1] = *(const short8*)(Qb + (size_t)(u * 16) * EMBED + 32 + fk);
    }

    const bf16_t* Kbase = Kp + (size_t)(b * SEQ) * EMBED + h * HDIM;
    const bf16_t* Vbase = Vt + ((size_t)(b * 1024 + h * HDIM) << 11);

    floatx4 o[4][4] = {};                     // O^T[u][d=t*16+quad*4+r][q=fr]
    float m[4] = {NEG_INF, NEG_INF, NEG_INF, NEG_INF};
    float l[4] = {};

    // Softmax for one subtile -> PV B-frag (P^T[kv][q]) via permlane quad-transpose.
    auto smax_pb = [&](const floatx4& sA, const floatx4& sB, float& m_u, float& l_u,
                       floatx4* o_u, const bool masked, const int off) -> short8 {
        float v0[4], v1[4];
        #pragma unroll
        for (int rr = 0; rr < 4; ++rr) {
            float a  = sA[rr];
            float bb = sB[rr];
            if (masked) {
                const int kq = (quad << 2) + rr;
                if (kq > off + fr)      a  = NEG_INF;
                if (kq + 16 > off + fr) bb = NEG_INF;
            }
            v0[rr] = a; v1[rr] = bb;
        }
        float mx = fmaxf(fmaxf(fmaxf(v0[0], v0[1]), fmaxf(v0[2], v0[3])),
                         fmaxf(fmaxf(v1[0], v1[1]), fmaxf(v1[2], v1[3])));
        if (__any(mx > m_u + 8.0f)) {             // rare path (~once per wave)
            mx = fmaxf(mx, __shfl_xor(mx, 16, 64));
            mx = fmaxf(mx, __shfl_xor(mx, 32, 64));
            const float mn = fmaxf(m_u, mx);
            const float al = fast_exp2(m_u - mn);
            m_u = mn;
            l_u *= al;
            #pragma unroll
            for (int t = 0; t < 4; ++t)           // O^T: q = fr for ALL values
                #pragma unroll
                for (int rr = 0; rr < 4; ++rr) o_u[t][rr] *= al;
        }
        float ls = 0.f;
        #pragma unroll
        for (int rr = 0; rr < 4; ++rr) {
            v0[rr] = fast_exp2(v0[rr] - m_u);     // bounded by 2^8 (defer-max)
            v1[rr] = fast_exp2(v1[rr] - m_u);
            ls += v0[rr] + v1[rr];
        }
        l_u += ls;                                // per-lane partial, no shfl
        unsigned c0p = pack_bf16x2(v0[0], v0[1]);
        unsigned c1p = pack_bf16x2(v0[2], v0[3]);
        unsigned d0p = pack_bf16x2(v1[0], v1[1]);
        unsigned d1p = pack_bf16x2(v1[2], v1[3]);
        permswap32(c0p, d0p);
        permswap32(c1p, d1p);
        permswap16(c0p, d0p);
        permswap16(c1p, d1p);
        uint4v wv; wv[0] = c0p; wv[1] = c1p; wv[2] = d0p; wv[3] = d1p;
        return __builtin_bit_cast(short8, wv);
    };

    short8 kf0, kf1, kf2, kf3;               // persistent K frags (rotated in place)

// (Re)load K frags for chunk CC into kf0-3
#define KLOADX(CC) do {                                                      \
        const int kvk_ = (CC) << 5;                                          \
        const bf16_t* Kr0_ = Kbase + (size_t)(kvk_ + fr) * EMBED;            \
        const bf16_t* Kr1_ = Kr0_ + (size_t)16 * EMBED;                      \
        kf0 = *(const short8*)(Kr0_ + fk);                                   \
        kf1 = *(const short8*)(Kr0_ + 32 + fk);                              \
        kf2 = *(const short8*)(Kr1_ + fk);                                   \
        kf3 = *(const short8*)(Kr1_ + 32 + fk);                              \
    } while (0)

// One kv chunk. V loaded at top (covered by softmax); K for CC+1 reloaded in
// place right after its last use (u==3 QK) -- register-neutral pipelining.
#define ITER(CC, MASKED, OFFB) do {                                          \
        const int kv0 = (CC) << 5;                                           \
        const short8 vf0 = *(const short8*)(Vbase + ((size_t)(fr)      << 11) + kv0 + fk); \
        const short8 vf1 = *(const short8*)(Vbase + ((size_t)(16 + fr) << 11) + kv0 + fk); \
        const short8 vf2 = *(const short8*)(Vbase + ((size_t)(32 + fr) << 11) + kv0 + fk); \
        const short8 vf3 = *(const short8*)(Vbase + ((size_t)(48 + fr) << 11) + kv0 + fk); \
        _Pragma("unroll")                                                    \
        for (int u = 0; u < 4; ++u) {                                        \
            floatx4 z0 = {}, z1 = {};                                        \
            __builtin_amdgcn_s_setprio(1);                                   \
            z0 = MFMA16(kf0, aq[u][0], z0); z0 = MFMA16(kf1, aq[u][1], z0);  \
            z1 = MFMA16(kf2, aq[u][0], z1); z1 = MFMA16(kf3, aq[u][1], z1);  \
            __builtin_amdgcn_s_setprio(0);                                   \
            if (u == 3 && (CC) + 1 < c1) KLOADX((CC) + 1);                   \
            const short8 pb = smax_pb(z0, z1, m[u], l[u], o[u],              \
                                      MASKED, u * 16 + (OFFB));              \
            __builtin_amdgcn_s_setprio(1);                                   \
            o[u][0] = MFMA16(vf0, pb, o[u][0]);                              \
            o[u][1] = MFMA16(vf1, pb, o[u][1]);                              \
            o[u][2] = MFMA16(vf2, pb, o[u][2]);                              \
            o[u][3] = MFMA16(vf3, pb, o[u][3]);                              \
            __builtin_amdgcn_s_setprio(0);                                   \
        }                                                                    \
    } while (0)

    if (c1 > c0) {
        KLOADX(c0);
        int c = c0;
        const int dcl = (d0 < c1) ? d0 : c1;     // clamp masked start into range
        const int cmu = (dcl > c0) ? dcl : c0;   // unmasked end
        for (; c < cmu; ++c) ITER(c, false, 0);
        for (; c < c1; ++c) ITER(c, true, (c == d0) ? 0 : -32);
    }

#undef ITER
#undef KLOADX

    // deferred cross-quad l reduction (once)
    #pragma unroll
    for (int u = 0; u < 4; ++u) {
        float t = __shfl_xor(l[u], 16, 64); l[u] += t;
        t = __shfl_xor(l[u], 32, 64);       l[u] += t;
    }

    // publish partials: waves 1..3 -> LDS O; all waves -> m,l
    if (wave != 0) {
        #pragma unroll
        for (int u = 0; u < 4; ++u)
            #pragma unroll
            for (int t = 0; t < 4; ++t)
                *(floatx4*)&Obuf[wave - 1][u * 16 + fr][(t << 4) + (quad << 2)] = o[u][t];
    }
    if (quad == 0) {
        #pragma unroll
        for (int u = 0; u < 4; ++u) {
            Mbuf[wave][u * 16 + fr] = m[u];
            Lbuf[wave][u * 16 + fr] = l[u];
        }
    }
    __syncthreads();

    if (wave == 0) {
        // 4-way combine: O = sum_s w_s O_s / sum_s w_s l_s, w_s = 2^(m_s - M)
        #pragma unroll
        for (int u = 0; u < 4; ++u) {
            const int row = u * 16 + fr;
            const float m1 = Mbuf[1][row], m2 = Mbuf[2][row], m3 = Mbuf[3][row];
            const float l1 = Lbuf[1][row], l2 = Lbuf[2][row], l3 = Lbuf[3][row];
            const float M  = fmaxf(fmaxf(m[u], m1), fmaxf(m2, m3));
            const float w0 = fast_exp2(m[u] - M);
            const float w1 = fast_exp2(m1 - M);
            const float w2 = fast_exp2(m2 - M);
            const float w3 = fast_exp2(m3 - M);
            const float rd = 1.0f / (w0 * l[u] + w1 * l1 + w2 * l2 + w3 * l3);
            // no quad term in the base -- col below carries it (R8 bugfix)
            bf16_t* outp = AO + (size_t)(b * SEQ + q0 + row) * EMBED + h * HDIM;
            #pragma unroll
            for (int t = 0; t < 4; ++t) {
                const int col = (t << 4) + (quad << 2);
                floatx4 acc = o[u][t];
                const floatx4 p1 = *(const floatx4*)&Obuf[0][row][col];
                const floatx4 p2 = *(const floatx4*)&Obuf[1][row][col];
                const floatx4 p3 = *(const floatx4*)&Obuf[2][row][col];
                short4v pk;
                #pragma unroll
                for (int rr = 0; rr < 4; ++rr) {
                    const float v = w0 * acc[rr] + w1 * p1[rr] + w2 * p2[rr] + w3 * p3[rr];
                    pk[rr] = bf16_bits(v * rd);
                }
                *(short4v*)(outp + col) = pk;
            }
        }
    }
}

extern "C" void kernel_launch(void* const* d_in, const int* in_sizes, int n_in,
                              void* d_out, int out_size, void* d_ws, size_t ws_size,
                              hipStream_t stream)
{
    (void)in_sizes; (void)n_in; (void)out_size; (void)ws_size;
    const float* q  = (const float*)d_in[0];
    const float* k  = (const float*)d_in[1];
    const float* v  = (const float*)d_in[2];
    const float* Wq = (const float*)d_in[3];
    const float* bq = (const float*)d_in[4];
    const float* Wk = (const float*)d_in[5];
    const float* bk = (const float*)d_in[6];
    const float* Wv = (const float*)d_in[7];
    const float* bv = (const float*)d_in[8];
    const float* Wo = (const float*)d_in[9];
    const float* bo = (const float*)d_in[10];
    // d_in[11] = attn_mask: fixed causal tril, handled analytically.

    const size_t NX = (size_t)MTOT * EMBED;   // 4M
    const size_t NW = (size_t)EMBED * EMBED;  // 1M
    bf16_t* Qx  = (bf16_t*)d_ws;
    bf16_t* Kx  = Qx  + NX;
    bf16_t* Vx  = Kx  + NX;
    bf16_t* Wqb = Vx  + NX;
    bf16_t* Wkb = Wqb + NW;
    bf16_t* Wvb = Wkb + NW;
    bf16_t* Wob = Wvb + NW;
    bf16_t* Qp  = Wob + NW;
    bf16_t* Kp  = Qp  + NX;
    bf16_t* Vtp = Kp  + NX;   // transposed: [b*1024 + d_global][s]
    bf16_t* AO  = Vtp + NX;   // total 32M bf16 = 64 MB

    dim3 blk(256);
    cvt_all<<<dim3(4096, 7), blk, 0, stream>>>(q, k, v, Wq, Wk, Wv, Wo,
                                               Qx, Kx, Vx, Wqb, Wkb, Wvb, Wob);
    qkv_proj<<<dim3(256, 1, 3), blk, 0, stream>>>(Qx, Kx, Vx, Wqb, Wkb, Wvb,
                                                  bq, bk, bv, Qp, Kp, Vtp);
    attn_causal<<<dim3(1024), blk, 0, stream>>>(Qp, Kp, Vtp, AO);
    out_proj<<<dim3(512), blk, 0, stream>>>(AO, Wob, bo, (float*)d_out);
}

// Round 15
// 231.904 us; speedup vs baseline: 1.2446x; 1.0028x over previous
//
#include <hip/hip_runtime.h>
#include <hip/hip_bf16.h>
#include <stdint.h>
#include <stddef.h>

typedef __hip_bfloat16 bf16_t;
typedef __attribute__((ext_vector_type(8))) short short8;
typedef __attribute__((ext_vector_type(4))) short short4v;
typedef __attribute__((ext_vector_type(4))) float floatx4;
typedef __attribute__((ext_vector_type(4))) unsigned uint4v;
typedef __attribute__((ext_vector_type(2))) unsigned uint2v;

#define EMBED 1024
#define NHEAD 16
#define HDIM  64
#define BATCH 2
#define SEQ   2048
#define MTOT  (BATCH*SEQ)
#define NEG_INF (-1e30f)
// 1/sqrt(64) * log2(e): softmax carried in exp2 domain (folded into Q projection)
#define SCALE2 0.18033688011112042f

#define MFMA16(a,b,c) __builtin_amdgcn_mfma_f32_16x16x32_bf16(a,b,c,0,0,0)

static __device__ __forceinline__ short bf16_bits(float x) {
    return __builtin_bit_cast(short, __float2bfloat16(x));
}

static __device__ __forceinline__ float fast_exp2(float x) {
#if __has_builtin(__builtin_amdgcn_exp2f)
    return __builtin_amdgcn_exp2f(x);
#else
    return __expf(x * 0.6931471805599453f);
#endif
}

// two bf16 (RTNE) packed in a u32; compiler fuses to v_cvt_pk_bf16_f32 (m240)
static __device__ __forceinline__ unsigned pack_bf16x2(float lo, float hi) {
    const unsigned a = (unsigned)(unsigned short)bf16_bits(lo);
    const unsigned b = (unsigned)(unsigned short)bf16_bits(hi);
    return a | (b << 16);
}

// gfx950 permlane swaps (verified R4: absmax unchanged vs LDS path)
static __device__ __forceinline__ void permswap32(unsigned& a, unsigned& b) {
#if __has_builtin(__builtin_amdgcn_permlane32_swap)
    uint2v r = __builtin_amdgcn_permlane32_swap(a, b, false, false);
    a = r[0]; b = r[1];
#else
    asm volatile("v_permlane32_swap_b32 %0, %1" : "+v"(a), "+v"(b));
#endif
}
static __device__ __forceinline__ void permswap16(unsigned& a, unsigned& b) {
#if __has_builtin(__builtin_amdgcn_permlane16_swap)
    uint2v r = __builtin_amdgcn_permlane16_swap(a, b, false, false);
    a = r[0]; b = r[1];
#else
    asm volatile("v_permlane16_swap_b32 %0, %1" : "+v"(a), "+v"(b));
#endif
}

// async global->LDS, 16B per lane; lds ptr must be wave-uniform (HW: base + lane*16)
static __device__ __forceinline__ void async_ld16(const bf16_t* g, short* l) {
    __builtin_amdgcn_global_load_lds(
        (const __attribute__((address_space(1))) void*)g,
        (__attribute__((address_space(3))) void*)l,
        16, 0, 0);
}

static __device__ __forceinline__ void store_out(float* p, float v)  { *p = v; }
static __device__ __forceinline__ void store_out(bf16_t* p, float v) { *p = __float2bfloat16(v); }

// fp32 -> bf16 (RTNE) for q,k,v (4M each) and Wq,Wk,Wv,Wo (1M each). grid.y selects tensor.
__global__ __launch_bounds__(256)
void cvt_all(const float* __restrict__ q, const float* __restrict__ k, const float* __restrict__ v,
             const float* __restrict__ wq, const float* __restrict__ wk,
             const float* __restrict__ wv, const float* __restrict__ wo,
             bf16_t* __restrict__ Qx, bf16_t* __restrict__ Kx, bf16_t* __restrict__ Vx,
             bf16_t* __restrict__ Wqb, bf16_t* __restrict__ Wkb,
             bf16_t* __restrict__ Wvb, bf16_t* __restrict__ Wob)
{
    const float* s; bf16_t* d; int n;
    switch (blockIdx.y) {
        case 0:  s = q;  d = Qx;  n = MTOT * EMBED;  break;
        case 1:  s = k;  d = Kx;  n = MTOT * EMBED;  break;
        case 2:  s = v;  d = Vx;  n = MTOT * EMBED;  break;
        case 3:  s = wq; d = Wqb; n = EMBED * EMBED; break;
        case 4:  s = wk; d = Wkb; n = EMBED * EMBED; break;
        case 5:  s = wv; d = Wvb; n = EMBED * EMBED; break;
        default: s = wo; d = Wob; n = EMBED * EMBED; break;
    }
    const int i4 = (int)blockIdx.x * 256 + (int)threadIdx.x;   // float4 index
    if (i4 * 4 < n) {
        const float4 f = ((const float4*)s)[i4];
        short4v o;
        o[0] = bf16_bits(f.x); o[1] = bf16_bits(f.y);
        o[2] = bf16_bits(f.z); o[3] = bf16_bits(f.w);
        ((short4v*)d)[i4] = o;
    }
}

// C[M,N] = (A[M,K] @ W[N,K]^T + bias) * scale, bf16 in, fp32 accumulate.
// M=4096, N=K=1024 fixed. BM x 128 tile, BK=64 (two 32-col halves per barrier pair).
// 256 thr (4 waves 2x2). VT=true: transposed output (for V: [b, d_global, s]).
// v9 (R12-verified): shared staging hoisted to callers (one 32KB set, not one per
// template instantiation); XCD-chunked block swizzle for A-panel L2 locality.
template <typename OutT, bool VT, int BM>
static __device__ __forceinline__ void gemm_tile(
    const bf16_t* __restrict__ A, const bf16_t* __restrict__ W,
    const float* __restrict__ bias, OutT* __restrict__ C, const float scale,
    short* __restrict__ As, short* __restrict__ Bs)
{
    constexpr int MI  = BM >> 5;            // A-frags per wave (4 or 2)
    constexpr int RPW = BM >> 2;            // A rows staged per wave
    constexpr int NBM = 4096 / BM;          // 32 or 64
    constexpr int BMC = NBM / 8;            // bm chunk per XCD (4 or 8)
    const int N = 1024, K = 1024;

    const int tid  = threadIdx.x;
    const int wave = tid >> 6;
    const int lane = tid & 63;
    // XCD-chunked swizzle (bijective: bid = xcd + 8*(bml + BMC*bn))
    const int bid = (int)blockIdx.x;
    const int xcd = bid & 7;
    const int k8  = bid >> 3;
    const int bm  = xcd * BMC + (k8 & (BMC - 1));
    const int bn  = k8 / BMC;
    const int m0 = bm * BM, n0 = bn << 7;

    const int wm = ((wave >> 1) & 1) * (BM >> 1);
    const int wn = (wave & 1) << 6;

    floatx4 acc[MI][4] = {};

    const int srowA = wave * RPW + (lane >> 2);
    const int srowB = (wave << 5) + (lane >> 2);
    const int scol  = (lane & 3) << 3;            // element col: 0,8,16,24
    const bf16_t* gA = A + (size_t)(m0 + srowA) * K + scol;
    const bf16_t* gB = W + (size_t)(n0 + srowB) * K + scol;

    const int fr = lane & 15;
    const int fk = (lane >> 4) << 3;

    for (int k0 = 0; k0 < K; k0 += 64) {
        __syncthreads();
        short* a0 = As + wave * RPW * 32;             // half 0
        short* a1 = As + BM * 32 + wave * RPW * 32;   // half 1
        short* b0 = Bs + (wave << 10);
        short* b1 = Bs + 128 * 32 + (wave << 10);
        async_ld16(gA,      a0);
        async_ld16(gA + 32, a1);
        if constexpr (BM == 128) {
            async_ld16(gA + (size_t)16 * K,      a0 + 512);
            async_ld16(gA + (size_t)16 * K + 32, a1 + 512);
        }
        async_ld16(gB,      b0);
        async_ld16(gB + 32, b1);
        async_ld16(gB + (size_t)16 * K,      b0 + 512);
        async_ld16(gB + (size_t)16 * K + 32, b1 + 512);
        gA += 64; gB += 64;
        __syncthreads();                      // drains vmcnt before barrier (m97-verified)

        #pragma unroll
        for (int hh = 0; hh < 2; ++hh) {
            short8 af[MI], bfr[4];
            #pragma unroll
            for (int i = 0; i < MI; ++i)
                af[i] = *(const short8*)&As[hh * BM * 32 + (wm + (i << 4) + fr) * 32 + fk];
            #pragma unroll
            for (int j = 0; j < 4; ++j)
                bfr[j] = *(const short8*)&Bs[hh * 128 * 32 + (wn + (j << 4) + fr) * 32 + fk];
            #pragma unroll
            for (int i = 0; i < MI; ++i)
                #pragma unroll
                for (int j = 0; j < 4; ++j)
                    acc[i][j] = MFMA16(af[i], bfr[j], acc[i][j]);
        }
    }

    // epilogue: C/D layout col=lane&15, row=quad*4+r
    const int q4 = (lane >> 4) << 2;
    #pragma unroll
    for (int j = 0; j < 4; ++j) {
        const int n = n0 + wn + (j << 4) + fr;
        const float bv = bias[n];
        #pragma unroll
        for (int i = 0; i < MI; ++i) {
            const int mb = m0 + wm + (i << 4) + q4;
            if (VT) {
                const int bb = mb >> 11, ss = mb & 2047;
                short4v pk;
                #pragma unroll
                for (int r = 0; r < 4; ++r)
                    pk[r] = bf16_bits((acc[i][j][r] + bv) * scale);
                *(short4v*)((bf16_t*)C + ((size_t)(bb * 1024 + n) << 11) + ss) = pk;
            } else {
                #pragma unroll
                for (int r = 0; r < 4; ++r)
                    store_out(&C[(size_t)(mb + r) * N + n], (acc[i][j][r] + bv) * scale);
            }
        }
    }
}

__global__ __launch_bounds__(256)
void qkv_proj(const bf16_t* __restrict__ xq, const bf16_t* __restrict__ xk,
              const bf16_t* __restrict__ xv,
              const bf16_t* __restrict__ Wq, const bf16_t* __restrict__ Wk,
              const bf16_t* __restrict__ Wv,
              const float* __restrict__ bq, const float* __restrict__ bk,
              const float* __restrict__ bv,
              bf16_t* __restrict__ Qp, bf16_t* __restrict__ Kp, bf16_t* __restrict__ Vtp)
{
    // ONE shared staging set for all branches (R12-verified: was duplicated per
    // template instantiation -> 64KB/block, halved occupancy)
    __shared__ alignas(16) short As[128 * 64];
    __shared__ alignas(16) short Bs[128 * 64];
    // Q carries the softmax scale (exp2-domain): folded here, free in attn hot loop
    if (blockIdx.z == 0)      gemm_tile<bf16_t, false, 128>(xq, Wq, bq, Qp, SCALE2, As, Bs);
    else if (blockIdx.z == 1) gemm_tile<bf16_t, false, 128>(xk, Wk, bk, Kp, 1.0f, As, Bs);
    else                      gemm_tile<bf16_t, true , 128>(xv, Wv, bv, Vtp, 1.0f, As, Bs);
}

__global__ __launch_bounds__(256)
void out_proj(const bf16_t* __restrict__ AO, const bf16_t* __restrict__ Wo,
              const float* __restrict__ bo, float* __restrict__ out)
{
    __shared__ alignas(16) short As[64 * 64];
    __shared__ alignas(16) short Bs[128 * 64];
    gemm_tile<float, false, 64>(AO, Wo, bo, out, 1.0f, As, Bs);
}

// Flash attention, causal. QK^T as S^T = K·Q^T (C-layout: q = lane&15).
// v12: phase-batched schedule (v6c structure, R9-correctness-verified) at the
//   spill-free launch_bounds(256,2) + kf in-place rotation (R14-verified):
//   R14 showed K-prefetch is null -> the binding term is the SERIAL per-u chain
//   (4x QK->SM->PV in sequence; SM is ~40 dependent VALU ops, exposed at
//   2 waves/SIMD). Batch the phases: QK x4 (one MFMA cluster) -> K rotate ->
//   smax x4 (four INDEPENDENT chains, scheduler interleaves them) -> PV x16
//   (one cluster). Register estimate: ~124 arch + 64 accum <= the ~128-arch
//   allocator heuristic (R13) -> no spill expected (guard: WRITE stays 8.2MB).
//   setprio at cluster granularity only (less fencing than R14's per-u toggles).
//   Structure (R9-R14 verified): 1024 blocks x 4 waves; waves split the q-tile's
//   kv range in quarters; partials combined IN LDS (waves 1-3 publish O/m/l,
//   wave 0 combines in regs). Zero extra HBM traffic, no combine kernel.
//  - permlane in-register P^T (R4-verified), O^T layout, defer-max gate,
//    per-lane l partials.
//  - masked chunks (kv >= q0): c >= nch-2 in a short second loop (offb 0 / -32).
__global__ __launch_bounds__(256, 2)
void attn_causal(const bf16_t* __restrict__ Qp, const bf16_t* __restrict__ Kp,
                 const bf16_t* __restrict__ Vt, bf16_t* __restrict__ AO)
{
    __shared__ alignas(16) float Obuf[3][64][68];  // partials of waves 1..3; 272B rows
    __shared__ float Mbuf[4][64];
    __shared__ float Lbuf[4][64];

    const int tid  = (int)threadIdx.x;
    const int wave = tid >> 6;            // 0..3: kv quarter
    const int lane = tid & 63;
    const int bid  = (int)blockIdx.x;
    const int bh   = bid & 31;            // bh%8 == XCD for all blocks of this head
    const int tile = 31 - (bid >> 5);     // longest-first
    const int b = bh >> 4, h = bh & 15;
    const int q0  = tile << 6;
    const int nch = 2 * tile + 2;
    const int c0  = (wave * nch) >> 2;
    const int c1  = ((wave + 1) * nch) >> 2;
    const int d0  = nch - 2;              // first diag-masked chunk

    const int fr   = lane & 15;
    const int quad = lane >> 4;
    const int fk   = quad << 3;

    // Q B-frags for 4 subtiles (rows q0 + u*16 + fr), Q pre-scaled by SCALE2
    const bf16_t* Qb = Qp + (size_t)(b * SEQ + q0 + fr) * EMBED + h * HDIM;
    short8 aq[4][2];
    #pragma unroll
    for (int u = 0; u < 4; ++u) {
        aq[u][0] = *(const short8*)(Qb + (size_t)(u * 16) * EMBED + fk);
        aq[u][1] = *(const short8*)(Qb + (size_t)(u * 16) * EMBED + 32 + fk);
    }

    const bf16_t* Kbase = Kp + (size_t)(b * SEQ) * EMBED + h * HDIM;
    const bf16_t* Vbase = Vt + ((size_t)(b * 1024 + h * HDIM) << 11);

    floatx4 o[4][4] = {};                     // O^T[u][d=t*16+quad*4+r][q=fr]
    float m[4] = {NEG_INF, NEG_INF, NEG_INF, NEG_INF};
    float l[4] = {};

    // Softmax for one subtile -> PV B-frag (P^T[kv][q]) via permlane quad-transpose.
    auto smax_pb = [&](const floatx4& sA, const floatx4& sB, float& m_u, float& l_u,
                       floatx4* o_u, const bool masked, const int off) -> short8 {
        float v0[4], v1[4];
        #pragma unroll
        for (int rr = 0; rr < 4; ++rr) {
            float a  = sA[rr];
            float bb = sB[rr];
            if (masked) {
                const int kq = (quad << 2) + rr;
                if (kq > off + fr)      a  = NEG_INF;
                if (kq + 16 > off + fr) bb = NEG_INF;
            }
            v0[rr] = a; v1[rr] = bb;
        }
        float mx = fmaxf(fmaxf(fmaxf(v0[0], v0[1]), fmaxf(v0[2], v0[3])),
                         fmaxf(fmaxf(v1[0], v1[1]), fmaxf(v1[2], v1[3])));
        if (__any(mx > m_u + 8.0f)) {             // rare path (~once per wave)
            mx = fmaxf(mx, __shfl_xor(mx, 16, 64));
            mx = fmaxf(mx, __shfl_xor(mx, 32, 64));
            const float mn = fmaxf(m_u, mx);
            const float al = fast_exp2(m_u - mn);
            m_u = mn;
            l_u *= al;
            #pragma unroll
            for (int t = 0; t < 4; ++t)           // O^T: q = fr for ALL values
                #pragma unroll
                for (int rr = 0; rr < 4; ++rr) o_u[t][rr] *= al;
        }
        float ls = 0.f;
        #pragma unroll
        for (int rr = 0; rr < 4; ++rr) {
            v0[rr] = fast_exp2(v0[rr] - m_u);     // bounded by 2^8 (defer-max)
            v1[rr] = fast_exp2(v1[rr] - m_u);
            ls += v0[rr] + v1[rr];
        }
        l_u += ls;                                // per-lane partial, no shfl
        unsigned c0p = pack_bf16x2(v0[0], v0[1]);
        unsigned c1p = pack_bf16x2(v0[2], v0[3]);
        unsigned d0p = pack_bf16x2(v1[0], v1[1]);
        unsigned d1p = pack_bf16x2(v1[2], v1[3]);
        permswap32(c0p, d0p);
        permswap32(c1p, d1p);
        permswap16(c0p, d0p);
        permswap16(c1p, d1p);
        uint4v wv; wv[0] = c0p; wv[1] = c1p; wv[2] = d0p; wv[3] = d1p;
        return __builtin_bit_cast(short8, wv);
    };

    short8 kf0, kf1, kf2, kf3;               // persistent K frags (rotated in place)

// (Re)load K frags for chunk CC into kf0-3
#define KLOADX(CC) do {                                                      \
        const int kvk_ = (CC) << 5;                                          \
        const bf16_t* Kr0_ = Kbase + (size_t)(kvk_ + fr) * EMBED;            \
        const bf16_t* Kr1_ = Kr0_ + (size_t)16 * EMBED;                      \
        kf0 = *(const short8*)(Kr0_ + fk);                                   \
        kf1 = *(const short8*)(Kr0_ + 32 + fk);                              \
        kf2 = *(const short8*)(Kr1_ + fk);                                   \
        kf3 = *(const short8*)(Kr1_ + 32 + fk);                              \
    } while (0)

// One kv chunk, PHASE-BATCHED (v12): QK x4 cluster -> K rotate -> smax x4
// (independent chains interleave) -> PV x16 cluster.
#define ITER(CC, MASKED, OFFB) do {                                          \
        const int kv0 = (CC) << 5;                                           \
        short8 vf[4];                                                        \
        _Pragma("unroll")                                                    \
        for (int t = 0; t < 4; ++t)                                          \
            vf[t] = *(const short8*)(Vbase + ((size_t)((t << 4) + fr) << 11) + kv0 + fk); \
        floatx4 s0[4], s1[4];                                                \
        __builtin_amdgcn_s_setprio(1);                                       \
        _Pragma("unroll")                                                    \
        for (int u = 0; u < 4; ++u) {                                        \
            floatx4 z0 = {}, z1 = {};                                        \
            z0 = MFMA16(kf0, aq[u][0], z0); z0 = MFMA16(kf1, aq[u][1], z0);  \
            z1 = MFMA16(kf2, aq[u][0], z1); z1 = MFMA16(kf3, aq[u][1], z1);  \
            s0[u] = z0; s1[u] = z1;                                          \
        }                                                                    \
        __builtin_amdgcn_s_setprio(0);                                       \
        if ((CC) + 1 < c1) KLOADX((CC) + 1);                                 \
        short8 pb[4];                                                        \
        _Pragma("unroll")                                                    \
        for (int u = 0; u < 4; ++u)                                          \
            pb[u] = smax_pb(s0[u], s1[u], m[u], l[u], o[u],                  \
                            MASKED, u * 16 + (OFFB));                        \
        __builtin_amdgcn_s_setprio(1);                                       \
        _Pragma("unroll")                                                    \
        for (int u = 0; u < 4; ++u)                                          \
            _Pragma("unroll")                                                \
            for (int t = 0; t < 4; ++t)                                      \
                o[u][t] = MFMA16(vf[t], pb[u], o[u][t]);                     \
        __builtin_amdgcn_s_setprio(0);                                       \
    } while (0)

    if (c1 > c0) {
        KLOADX(c0);
        int c = c0;
        const int dcl = (d0 < c1) ? d0 : c1;     // clamp masked start into range
        const int cmu = (dcl > c0) ? dcl : c0;   // unmasked end
        for (; c < cmu; ++c) ITER(c, false, 0);
        for (; c < c1; ++c) ITER(c, true, (c == d0) ? 0 : -32);
    }

#undef ITER
#undef KLOADX

    // deferred cross-quad l reduction (once)
    #pragma unroll
    for (int u = 0; u < 4; ++u) {
        float t = __shfl_xor(l[u], 16, 64); l[u] += t;
        t = __shfl_xor(l[u], 32, 64);       l[u] += t;
    }

    // publish partials: waves 1..3 -> LDS O; all waves -> m,l
    if (wave != 0) {
        #pragma unroll
        for (int u = 0; u < 4; ++u)
            #pragma unroll
            for (int t = 0; t < 4; ++t)
                *(floatx4*)&Obuf[wave - 1][u * 16 + fr][(t << 4) + (quad << 2)] = o[u][t];
    }
    if (quad == 0) {
        #pragma unroll
        for (int u = 0; u < 4; ++u) {
            Mbuf[wave][u * 16 + fr] = m[u];
            Lbuf[wave][u * 16 + fr] = l[u];
        }
    }
    __syncthreads();

    if (wave == 0) {
        // 4-way combine: O = sum_s w_s O_s / sum_s w_s l_s, w_s = 2^(m_s - M)
        #pragma unroll
        for (int u = 0; u < 4; ++u) {
            const int row = u * 16 + fr;
            const float m1 = Mbuf[1][row], m2 = Mbuf[2][row], m3 = Mbuf[3][row];
            const float l1 = Lbuf[1][row], l2 = Lbuf[2][row], l3 = Lbuf[3][row];
            const float M  = fmaxf(fmaxf(m[u], m1), fmaxf(m2, m3));
            const float w0 = fast_exp2(m[u] - M);
            const float w1 = fast_exp2(m1 - M);
            const float w2 = fast_exp2(m2 - M);
            const float w3 = fast_exp2(m3 - M);
            const float rd = 1.0f / (w0 * l[u] + w1 * l1 + w2 * l2 + w3 * l3);
            // no quad term in the base -- col below carries it (R8 bugfix)
            bf16_t* outp = AO + (size_t)(b * SEQ + q0 + row) * EMBED + h * HDIM;
            #pragma unroll
            for (int t = 0; t < 4; ++t) {
                const int col = (t << 4) + (quad << 2);
                floatx4 acc = o[u][t];
                const floatx4 p1 = *(const floatx4*)&Obuf[0][row][col];
                const floatx4 p2 = *(const floatx4*)&Obuf[1][row][col];
                const floatx4 p3 = *(const floatx4*)&Obuf[2][row][col];
                short4v pk;
                #pragma unroll
                for (int rr = 0; rr < 4; ++rr) {
                    const float v = w0 * acc[rr] + w1 * p1[rr] + w2 * p2[rr] + w3 * p3[rr];
                    pk[rr] = bf16_bits(v * rd);
                }
                *(short4v*)(outp + col) = pk;
            }
        }
    }
}

extern "C" void kernel_launch(void* const* d_in, const int* in_sizes, int n_in,
                              void* d_out, int out_size, void* d_ws, size_t ws_size,
                              hipStream_t stream)
{
    (void)in_sizes; (void)n_in; (void)out_size; (void)ws_size;
    const float* q  = (const float*)d_in[0];
    const float* k  = (const float*)d_in[1];
    const float* v  = (const float*)d_in[2];
    const float* Wq = (const float*)d_in[3];
    const float* bq = (const float*)d_in[4];
    const float* Wk = (const float*)d_in[5];
    const float* bk = (const float*)d_in[6];
    const float* Wv = (const float*)d_in[7];
    const float* bv = (const float*)d_in[8];
    const float* Wo = (const float*)d_in[9];
    const float* bo = (const float*)d_in[10];
    // d_in[11] = attn_mask: fixed causal tril, handled analytically.

    const size_t NX = (size_t)MTOT * EMBED;   // 4M
    const size_t NW = (size_t)EMBED * EMBED;  // 1M
    bf16_t* Qx  = (bf16_t*)d_ws;
    bf16_t* Kx  = Qx  + NX;
    bf16_t* Vx  = Kx  + NX;
    bf16_t* Wqb = Vx  + NX;
    bf16_t* Wkb = Wqb + NW;
    bf16_t* Wvb = Wkb + NW;
    bf16_t* Wob = Wvb + NW;
    bf16_t* Qp  = Wob + NW;
    bf16_t* Kp  = Qp  + NX;
    bf16_t* Vtp = Kp  + NX;   // transposed: [b*1024 + d_global][s]
    bf16_t* AO  = Vtp + NX;   // total 32M bf16 = 64 MB

    dim3 blk(256);
    cvt_all<<<dim3(4096, 7), blk, 0, stream>>>(q, k, v, Wq, Wk, Wv, Wo,
                                               Qx, Kx, Vx, Wqb, Wkb, Wvb, Wob);
    qkv_proj<<<dim3(256, 1, 3), blk, 0, stream>>>(Qx, Kx, Vx, Wqb, Wkb, Wvb,
                                                  bq, bk, bv, Qp, Kp, Vtp);
    attn_causal<<<dim3(1024), blk, 0, stream>>>(Qp, Kp, Vtp, AO);
    out_proj<<<dim3(512), blk, 0, stream>>>(AO, Wob, bo, (float*)d_out);
}